// Round 21
// baseline (1078.749 us; speedup 1.0000x reference)
//
#include <hip/hip_runtime.h>
#include <hip/hip_bf16.h>

#define LL 128
#define BB 128
#define AA 512
#define II 512
#define HH 1024
#define KK 1024   // I+A (W_ih row length)
#define NTEAM 8   // 8 teams x 16 batches
#define NDG 32    // 32 dim-groups x 32 dims
#define NBLK (NTEAM * NDG)   // 256 blocks

typedef __attribute__((ext_vector_type(8))) short short8;
typedef __attribute__((ext_vector_type(4))) float f32x4;
typedef __attribute__((ext_vector_type(4))) unsigned uint32x4;

static __device__ __forceinline__ unsigned short f2b(float x) {
    union { float f; unsigned u; } v; v.f = x;
    unsigned r = v.u + 0x7fffu + ((v.u >> 16) & 1u);
    return (unsigned short)(r >> 16);
}
static __device__ __forceinline__ float fast_sigmoid(float x) {
    return 1.f / (1.f + __expf(-x));
}
static __device__ __forceinline__ float fast_tanh(float x) {
    float e = __expf(2.f * x);
    return (e - 1.f) / (e + 1.f);
}

// device-coherent UC ops (proven rounds 4/7/8/9): bypass L1+L2, served at coherence point
static __device__ __forceinline__ short8 uc_load128(const unsigned short* p) {
    short8 r;
    asm volatile("global_load_dwordx4 %0, %1, off sc0 sc1" : "=v"(r) : "v"(p));
    return r;
}
static __device__ __forceinline__ void uc_store128(unsigned short* p, uint32x4 v) {
    asm volatile("global_store_dwordx4 %0, %1, off sc0 sc1" :: "v"(p), "v"(v) : "memory");
}
static __device__ __forceinline__ void uc_flag_store(unsigned int* p, unsigned v) {
    asm volatile("global_store_dword %0, %1, off sc0 sc1" :: "v"(p), "v"(v) : "memory");
}

// ---------------- pack kernels ----------------
__global__ void cast_kernel(const float* __restrict__ s, unsigned short* __restrict__ d, int n) {
    int stride = gridDim.x * blockDim.x;
    for (int i = blockIdx.x * blockDim.x + threadIdx.x; i < n; i += stride) d[i] = f2b(s[i]);
}

// ---------------- fused persistent LSTM (r20 + 1-step xa register prefetch) ----------------
// 256 blocks = 8 teams (16 batches) x 32 dim-groups (32 dims).
//   W_hh slice in REGISTERS; W_a slice in LDS (128 KB); base = W_x*inF once.
// Per step (3 barriers, r9/r17/r20-proven protocol):
//   [all] issue xa prefetch for step l+1 (flies under ~5us of step work);
//         W_a*a_l MFMA from REGISTER-resident fragments (no cold-load stall)
//   [w7]  poll 32 team flags (staggered double UC load)      -> B1
//   [all] UC h read + W_hh MFMA; ksl!=0 write red partials   -> B2
//   [gate] absorb red, gate math, hbuf write (no global st)  -> sync2
//   [w2]  line-dense h store, vmcnt(0) (h only), per-dg flag store
//   [gate] deferred out[] stores (drain under next poll wait).
// Race-freedom (r9): h store of step l happens after B1(l) => all team flags >= l
// => all blocks finished reading h_{l-1} => ping-pong overwrite safe.
__launch_bounds__(512, 2)
__global__ void lstm_kernel(const unsigned short* __restrict__ xa,    // [L*B][512] bf16
                            const float* __restrict__ inF,            // [B][512] f32
                            const unsigned short* __restrict__ wihb,  // [4096][1024] bf16
                            const unsigned short* __restrict__ whhb,  // [4096][1024] bf16
                            const float* __restrict__ bih,
                            const float* __restrict__ bhh,
                            const float* __restrict__ c0,             // [B][H] f32
                            unsigned short* __restrict__ hb,          // [2][B][H] bf16
                            unsigned int* __restrict__ flagsG,        // [NTEAM*NDG] zeroed
                            float* __restrict__ out) {                // hs | h_n | c_n
    __shared__ __attribute__((aligned(16))) unsigned short wa_lds[8 * 16 * 64 * 8]; // 128 KB
    __shared__ float red[2 * 3 * 64 * 17];                                          // ~26 KB
    __shared__ __attribute__((aligned(16))) unsigned short hbuf[16 * 32];           // 1 KB [b][d]

    const int tid  = threadIdx.x;
    const int lane = tid & 63;
    const int w    = tid >> 6;          // 8 waves
    const int nq   = w >> 2;            // dim-half (16 dims)
    const int ksl  = w & 3;             // K-slice (256)
    const int dg   = blockIdx.x & (NDG - 1);
    const int mg   = blockIdx.x >> 5;   // team
    const int j0   = dg * 32;
    const int b0   = mg * 16;
    const int d    = lane & 15;
    const int rg   = lane >> 4;

    // ---- W_hh slice into registers (pure bf16 short8 loads, no convert) ----
    short8 breg[4][8];
    #pragma unroll
    for (int t = 0; t < 4; ++t) {
        #pragma unroll
        for (int kf = 0; kf < 8; ++kf)
            breg[t][kf] = *(const short8*)&whhb[(size_t)(t * HH + j0 + nq * 16 + d) * HH + ksl * 256 + kf * 32 + rg * 8];
    }

    // ---- W_a slice into LDS (wave-private region), pure short8 copies ----
    #pragma unroll
    for (int t = 0; t < 4; ++t) {
        #pragma unroll
        for (int kf = 0; kf < 4; ++kf) {
            short8 v = *(const short8*)&wihb[(size_t)(t * HH + j0 + nq * 16 + d) * KK + II + ksl * 128 + kf * 32 + rg * 8];
            *(short8*)&wa_lds[(((size_t)w * 16 + t * 4 + kf) * 64 + lane) * 8] = v;
        }
    }

    // ---- base = W_x * inF (all-wave, K-slice 128 each) ----
    f32x4 bacc[4] = {};
    #pragma unroll
    for (int kf = 0; kf < 4; ++kf) {
        const float* xs = &inF[(size_t)(b0 + d) * II + ksl * 128 + kf * 32 + rg * 8];
        short8 xf;
        #pragma unroll
        for (int j = 0; j < 8; ++j) xf[j] = (short)f2b(xs[j]);
        #pragma unroll
        for (int t = 0; t < 4; ++t) {
            short8 wf = *(const short8*)&wihb[(size_t)(t * HH + j0 + nq * 16 + d) * KK + ksl * 128 + kf * 32 + rg * 8];
            bacc[t] = __builtin_amdgcn_mfma_f32_16x16x32_bf16(xf, wf, bacc[t], 0, 0, 0);
        }
    }
    if (ksl != 0) {
        float* sp = &red[(size_t)((nq * 3 + (ksl - 1)) * 64 + lane) * 17];
        #pragma unroll
        for (int t = 0; t < 4; ++t)
            #pragma unroll
            for (int r = 0; r < 4; ++r) sp[t * 4 + r] = bacc[t][r];
    }
    __syncthreads();
    float base_r[16], c_r[4];
    if (ksl == 0) {
        #pragma unroll
        for (int s = 0; s < 3; ++s) {
            const float* sp = &red[(size_t)((nq * 3 + s) * 64 + lane) * 17];
            #pragma unroll
            for (int t = 0; t < 4; ++t)
                #pragma unroll
                for (int r = 0; r < 4; ++r) bacc[t][r] += sp[t * 4 + r];
        }
        #pragma unroll
        for (int t = 0; t < 4; ++t) {
            float bias = bih[t * HH + j0 + nq * 16 + d] + bhh[t * HH + j0 + nq * 16 + d];
            #pragma unroll
            for (int r = 0; r < 4; ++r) base_r[t * 4 + r] = bacc[t][r] + bias;
        }
        #pragma unroll
        for (int r = 0; r < 4; ++r) c_r[r] = c0[(b0 + rg * 4 + r) * HH + j0 + nq * 16 + d];
    }
    __syncthreads();   // red free for the step loop

    unsigned int*       ourflag  = flagsG + mg * NDG + dg;
    const unsigned int* pollflag = flagsG + mg * NDG + (lane & 31);
    const unsigned short* apbase = xa + (size_t)(b0 + d) * AA + ksl * 128 + rg * 8;

    // ---- step body: aaf = this step's xa fragments (resident), aaf_n = prefetch target ----
    auto step_body = [&](int l, short8 (&aaf)[4], short8 (&aaf_n)[4]) {
        const unsigned short* hr = hb + (size_t)(l & 1) * (BB * HH);
        unsigned short*       hw = hb + (size_t)((l + 1) & 1) * (BB * HH);

        // prefetch next step's xa fragments (flies under ~5us of step-l work)
        if (l < LL - 1) {
            const unsigned short* apn = apbase + (size_t)(l + 1) * (BB * AA);
            #pragma unroll
            for (int kf = 0; kf < 4; ++kf) aaf_n[kf] = *(const short8*)(apn + kf * 32);
        }

        // ---- input projection W_a * a_l from register-resident fragments ----
        f32x4 acc[4] = {};
        #pragma unroll
        for (int kf = 0; kf < 4; ++kf)
            #pragma unroll
            for (int t = 0; t < 4; ++t) {
                short8 wfr = *(const short8*)&wa_lds[(((size_t)w * 16 + t * 4 + kf) * 64 + lane) * 8];
                acc[t] = __builtin_amdgcn_mfma_f32_16x16x32_bf16(aaf[kf], wfr, acc[t], 0, 0, 0);
            }

        // ---- single-poller (w7): staggered double poll, sampling period ~ RTT/2 ----
        if (l > 0 && w == 7) {
            const unsigned lim = (unsigned)l;
            unsigned fa, fb; int guard = 0;
            asm volatile("global_load_dword %0, %1, off sc0 sc1" : "=v"(fa) : "v"(pollflag) : "memory");
            __builtin_amdgcn_s_sleep(8);
            for (;;) {
                asm volatile("global_load_dword %0, %1, off sc0 sc1" : "=v"(fb) : "v"(pollflag) : "memory");
                asm volatile("s_waitcnt vmcnt(1)" ::: "memory");
                __builtin_amdgcn_sched_barrier(0);   // rule #18: pin check after wait
                if (!__any(fa < lim) || ++guard >= (1 << 18)) break;
                asm volatile("global_load_dword %0, %1, off sc0 sc1" : "=v"(fa) : "v"(pollflag) : "memory");
                asm volatile("s_waitcnt vmcnt(1)" ::: "memory");
                __builtin_amdgcn_sched_barrier(0);
                if (!__any(fb < lim) || ++guard >= (1 << 18)) break;
            }
            asm volatile("s_waitcnt vmcnt(0)" ::: "memory");
        }
        __syncthreads();   // B1

        // ---- UC h read + recurrent GEMM ----
        short8 af[8];
        const unsigned short* hp = hr + (size_t)(b0 + d) * HH + ksl * 256 + rg * 8;
        #pragma unroll
        for (int kf = 0; kf < 8; ++kf) af[kf] = uc_load128(hp + kf * 32);
        asm volatile("s_waitcnt vmcnt(0)" ::: "memory");
        __builtin_amdgcn_sched_barrier(0);

        #pragma unroll
        for (int kf = 0; kf < 8; ++kf)
            #pragma unroll
            for (int t = 0; t < 4; ++t)
                acc[t] = __builtin_amdgcn_mfma_f32_16x16x32_bf16(af[kf], breg[t][kf], acc[t], 0, 0, 0);

        if (ksl != 0) {
            float* sp = &red[(size_t)((nq * 3 + (ksl - 1)) * 64 + lane) * 17];
            #pragma unroll
            for (int t = 0; t < 4; ++t)
                #pragma unroll
                for (int r = 0; r < 4; ++r) sp[t * 4 + r] = acc[t][r];
        }
        __syncthreads();   // B2: partials ready

        // ---- gate waves: absorb, gate math, hbuf write; NO global stores here ----
        float h1v[4];
        if (ksl == 0) {
            #pragma unroll
            for (int s = 0; s < 3; ++s) {
                const float* sp = &red[(size_t)((nq * 3 + s) * 64 + lane) * 17];
                #pragma unroll
                for (int t = 0; t < 4; ++t)
                    #pragma unroll
                    for (int r = 0; r < 4; ++r) acc[t][r] += sp[t * 4 + r];
            }
            #pragma unroll
            for (int r = 0; r < 4; ++r) {
                float gi = acc[0][r] + base_r[0 + r];
                float gf = acc[1][r] + base_r[4 + r];
                float gg = acc[2][r] + base_r[8 + r];
                float go = acc[3][r] + base_r[12 + r];
                float ig = fast_sigmoid(gi);
                float fg = fast_sigmoid(gf);
                float og = fast_sigmoid(go);
                float gt = fast_tanh(gg);
                float c1 = fg * c_r[r] + ig * gt;
                float h1 = og * fast_tanh(c1);
                c_r[r] = c1;
                h1v[r] = h1;
                hbuf[(rg * 4 + r) * 32 + nq * 16 + d] = f2b(h1);
            }
        }
        __syncthreads();   // sync2: hbuf ready (empty vmcnt drain — no stores pending)

        // wave 2 (idle otherwise): line-dense h store (16 rows x 64 B) + flag
        if (w == 2 && l < LL - 1) {
            int row = lane >> 2, ch = lane & 3;
            uint32x4 hv = *(const uint32x4*)&hbuf[row * 32 + ch * 8];
            uc_store128(&hw[(size_t)(b0 + row) * HH + j0 + ch * 8], hv);
            asm volatile("s_waitcnt vmcnt(0)" ::: "memory");   // ONLY the h store in flight
            if (lane == 0) uc_flag_store(ourflag, (unsigned)(l + 1));
        }

        // ---- deferred out[] stores: drain later, under next step's poll wait ----
        if (ksl == 0) {
            #pragma unroll
            for (int r = 0; r < 4; ++r)
                out[((size_t)l * BB + (b0 + rg * 4 + r)) * HH + j0 + nq * 16 + d] = h1v[r];
            if (l == LL - 1) {
                #pragma unroll
                for (int r = 0; r < 4; ++r) {
                    out[(size_t)LL * BB * HH + (b0 + rg * 4 + r) * HH + j0 + nq * 16 + d] = h1v[r];
                    out[(size_t)LL * BB * HH + BB * HH + (b0 + rg * 4 + r) * HH + j0 + nq * 16 + d] = c_r[r];
                }
            }
        }
    };

    // prime xa fragments for l=0, then run steps in pairs with swapped register buffers
    short8 aafA[4], aafB[4];
    #pragma unroll
    for (int kf = 0; kf < 4; ++kf) aafA[kf] = *(const short8*)(apbase + kf * 32);

    for (int l = 0; l < LL; l += 2) {
        step_body(l,     aafA, aafB);
        step_body(l + 1, aafB, aafA);
    }
}

extern "C" void kernel_launch(void* const* d_in, const int* in_sizes, int n_in,
                              void* d_out, int out_size, void* d_ws, size_t ws_size,
                              hipStream_t stream) {
    const float* act = (const float*)d_in[0];
    const float* inF = (const float*)d_in[1];
    const float* h0  = (const float*)d_in[2];
    const float* c0  = (const float*)d_in[3];
    const float* Wih = (const float*)d_in[4];
    const float* Whh = (const float*)d_in[5];
    const float* bih = (const float*)d_in[6];
    const float* bhh = (const float*)d_in[7];
    float* out = (float*)d_out;

    char* p = (char*)d_ws;
    unsigned short* xa    = (unsigned short*)p; p += (size_t)LL * BB * AA * 2;   // 16.8 MB
    unsigned short* wihb  = (unsigned short*)p; p += (size_t)4 * HH * KK * 2;    //  8.4 MB
    unsigned short* whhb  = (unsigned short*)p; p += (size_t)4 * HH * HH * 2;    //  8.4 MB
    unsigned short* hb    = (unsigned short*)p; p += (size_t)2 * BB * HH * 2;    //  0.5 MB
    unsigned int*   flags = (unsigned int*)p;   p += NTEAM * NDG * sizeof(unsigned int);

    hipMemsetAsync(flags, 0, NTEAM * NDG * sizeof(unsigned int), stream);
    cast_kernel<<<dim3(2048), dim3(256), 0, stream>>>(act, xa, LL * BB * AA);
    cast_kernel<<<dim3(1024), dim3(256), 0, stream>>>(Wih, wihb, 4 * HH * KK);
    cast_kernel<<<dim3(1024), dim3(256), 0, stream>>>(Whh, whhb, 4 * HH * HH);
    cast_kernel<<<dim3(64), dim3(256), 0, stream>>>(h0, hb, BB * HH);

    void* args[] = { (void*)&xa, (void*)&inF, (void*)&wihb, (void*)&whhb, (void*)&bih,
                     (void*)&bhh, (void*)&c0, (void*)&hb, (void*)&flags, (void*)&out };
    hipLaunchCooperativeKernel((const void*)lstm_kernel, dim3(NBLK), dim3(512), args, 0, stream);
}

// Round 22
// 761.687 us; speedup vs baseline: 1.4163x; 1.4163x over previous
//
#include <hip/hip_runtime.h>
#include <hip/hip_bf16.h>

#define LL 128
#define BB 128
#define AA 512
#define II 512
#define HH 1024
#define KK 1024   // I+A (W_ih row length)
#define NTEAM 8   // 8 teams x 16 batches
#define NDG 32    // 32 dim-groups x 32 dims
#define NBLK (NTEAM * NDG)   // 256 blocks

typedef __attribute__((ext_vector_type(8))) short short8;
typedef __attribute__((ext_vector_type(4))) float f32x4;
typedef __attribute__((ext_vector_type(4))) unsigned uint32x4;

static __device__ __forceinline__ unsigned short f2b(float x) {
    union { float f; unsigned u; } v; v.f = x;
    unsigned r = v.u + 0x7fffu + ((v.u >> 16) & 1u);
    return (unsigned short)(r >> 16);
}
static __device__ __forceinline__ float fast_sigmoid(float x) {
    return 1.f / (1.f + __expf(-x));
}
static __device__ __forceinline__ float fast_tanh(float x) {
    float e = __expf(2.f * x);
    return (e - 1.f) / (e + 1.f);
}

// device-coherent UC ops (proven rounds 4/7/8/9): bypass L1+L2, served at coherence point
static __device__ __forceinline__ short8 uc_load128(const unsigned short* p) {
    short8 r;
    asm volatile("global_load_dwordx4 %0, %1, off sc0 sc1" : "=v"(r) : "v"(p));
    return r;
}
static __device__ __forceinline__ void uc_store128(unsigned short* p, uint32x4 v) {
    asm volatile("global_store_dwordx4 %0, %1, off sc0 sc1" :: "v"(p), "v"(v) : "memory");
}
static __device__ __forceinline__ void uc_flag_store(unsigned int* p, unsigned v) {
    asm volatile("global_store_dword %0, %1, off sc0 sc1" :: "v"(p), "v"(v) : "memory");
}

// ---------------- pack kernels ----------------
__global__ void cast_kernel(const float* __restrict__ s, unsigned short* __restrict__ d, int n) {
    int stride = gridDim.x * blockDim.x;
    for (int i = blockIdx.x * blockDim.x + threadIdx.x; i < n; i += stride) d[i] = f2b(s[i]);
}

// ---------------- fused persistent LSTM (r17 + bf16-W prologue + staggered poll) ----------------
// 256 blocks = 8 teams (16 batches) x 32 dim-groups (32 dims).
//   W_hh slice in REGISTERS (128 VGPR/thr, loaded as bf16 short8 — no convert);
//   W_a slice in LDS (128 KB); base = W_x*inF + biases once in prologue.
// Per step (3 barriers, r9/r17-proven protocol):
//   [all] W_a*a_l MFMA (no h dep, hides in poll wait; prev step's out[] drains here)
//   [w7]  poll 32 team flags — TWO staggered UC loads in flight (vmcnt(1) checks
//         the older while the newer flies; s_sleep spreads issue times) -> B1
//   [all] UC h read + W_hh MFMA; ksl!=0 write red partials  -> B2
//   [gate] absorb red, gate math, hbuf write (no global stores) -> sync2
//   [w2]  line-dense h store, vmcnt(0) (h only), per-dg flag store
//   [gate] deferred out[] stores (drain under next poll wait).
// Race-freedom (r9): h store of step l happens after B1(l) => all team flags >= l
// => all blocks finished reading h_{l-1} => ping-pong overwrite safe.
__launch_bounds__(512, 2)
__global__ void lstm_kernel(const unsigned short* __restrict__ xa,    // [L*B][512] bf16
                            const float* __restrict__ inF,            // [B][512] f32
                            const unsigned short* __restrict__ wihb,  // [4096][1024] bf16
                            const unsigned short* __restrict__ whhb,  // [4096][1024] bf16
                            const float* __restrict__ bih,
                            const float* __restrict__ bhh,
                            const float* __restrict__ c0,             // [B][H] f32
                            unsigned short* __restrict__ hb,          // [2][B][H] bf16
                            unsigned int* __restrict__ flagsG,        // [NTEAM*NDG] zeroed
                            float* __restrict__ out) {                // hs | h_n | c_n
    __shared__ __attribute__((aligned(16))) unsigned short wa_lds[8 * 16 * 64 * 8]; // 128 KB
    __shared__ float red[2 * 3 * 64 * 17];                                          // ~26 KB
    __shared__ __attribute__((aligned(16))) unsigned short hbuf[16 * 32];           // 1 KB [b][d]

    const int tid  = threadIdx.x;
    const int lane = tid & 63;
    const int w    = tid >> 6;          // 8 waves
    const int nq   = w >> 2;            // dim-half (16 dims)
    const int ksl  = w & 3;             // K-slice (256)
    const int dg   = blockIdx.x & (NDG - 1);
    const int mg   = blockIdx.x >> 5;   // team
    const int j0   = dg * 32;
    const int b0   = mg * 16;
    const int d    = lane & 15;
    const int rg   = lane >> 4;

    // ---- W_hh slice into registers (pure bf16 short8 loads, no convert) ----
    short8 breg[4][8];
    #pragma unroll
    for (int t = 0; t < 4; ++t) {
        #pragma unroll
        for (int kf = 0; kf < 8; ++kf)
            breg[t][kf] = *(const short8*)&whhb[(size_t)(t * HH + j0 + nq * 16 + d) * HH + ksl * 256 + kf * 32 + rg * 8];
    }

    // ---- W_a slice into LDS (wave-private region), pure short8 copies ----
    #pragma unroll
    for (int t = 0; t < 4; ++t) {
        #pragma unroll
        for (int kf = 0; kf < 4; ++kf) {
            short8 v = *(const short8*)&wihb[(size_t)(t * HH + j0 + nq * 16 + d) * KK + II + ksl * 128 + kf * 32 + rg * 8];
            *(short8*)&wa_lds[(((size_t)w * 16 + t * 4 + kf) * 64 + lane) * 8] = v;
        }
    }

    // ---- base = W_x * inF (all-wave, K-slice 128 each) ----
    f32x4 bacc[4] = {};
    #pragma unroll
    for (int kf = 0; kf < 4; ++kf) {
        const float* xs = &inF[(size_t)(b0 + d) * II + ksl * 128 + kf * 32 + rg * 8];
        short8 xf;
        #pragma unroll
        for (int j = 0; j < 8; ++j) xf[j] = (short)f2b(xs[j]);
        #pragma unroll
        for (int t = 0; t < 4; ++t) {
            short8 wf = *(const short8*)&wihb[(size_t)(t * HH + j0 + nq * 16 + d) * KK + ksl * 128 + kf * 32 + rg * 8];
            bacc[t] = __builtin_amdgcn_mfma_f32_16x16x32_bf16(xf, wf, bacc[t], 0, 0, 0);
        }
    }
    if (ksl != 0) {
        float* sp = &red[(size_t)((nq * 3 + (ksl - 1)) * 64 + lane) * 17];
        #pragma unroll
        for (int t = 0; t < 4; ++t)
            #pragma unroll
            for (int r = 0; r < 4; ++r) sp[t * 4 + r] = bacc[t][r];
    }
    __syncthreads();
    float base_r[16], c_r[4];
    if (ksl == 0) {
        #pragma unroll
        for (int s = 0; s < 3; ++s) {
            const float* sp = &red[(size_t)((nq * 3 + s) * 64 + lane) * 17];
            #pragma unroll
            for (int t = 0; t < 4; ++t)
                #pragma unroll
                for (int r = 0; r < 4; ++r) bacc[t][r] += sp[t * 4 + r];
        }
        #pragma unroll
        for (int t = 0; t < 4; ++t) {
            float bias = bih[t * HH + j0 + nq * 16 + d] + bhh[t * HH + j0 + nq * 16 + d];
            #pragma unroll
            for (int r = 0; r < 4; ++r) base_r[t * 4 + r] = bacc[t][r] + bias;
        }
        #pragma unroll
        for (int r = 0; r < 4; ++r) c_r[r] = c0[(b0 + rg * 4 + r) * HH + j0 + nq * 16 + d];
    }
    __syncthreads();   // red free for the step loop

    unsigned int*       ourflag  = flagsG + mg * NDG + dg;
    const unsigned int* pollflag = flagsG + mg * NDG + (lane & 31);

    for (int l = 0; l < LL; ++l) {
        const unsigned short* hr = hb + (size_t)(l & 1) * (BB * HH);
        unsigned short*       hw = hb + (size_t)((l + 1) & 1) * (BB * HH);

        // ---- input projection W_a * a_l (no h dependency; poll-shadow).
        //      Step l-1's deferred out-stores drain during this phase + B1.
        f32x4 acc[4] = {};
        {
            const unsigned short* ap = xa + ((size_t)l * BB + b0 + d) * AA + ksl * 128 + rg * 8;
            short8 aaf[4];
            #pragma unroll
            for (int kf = 0; kf < 4; ++kf) aaf[kf] = *(const short8*)(ap + kf * 32);
            #pragma unroll
            for (int kf = 0; kf < 4; ++kf)
                #pragma unroll
                for (int t = 0; t < 4; ++t) {
                    short8 wfr = *(const short8*)&wa_lds[(((size_t)w * 16 + t * 4 + kf) * 64 + lane) * 8];
                    acc[t] = __builtin_amdgcn_mfma_f32_16x16x32_bf16(aaf[kf], wfr, acc[t], 0, 0, 0);
                }
        }

        // ---- single-poller (w7): staggered double poll, sampling period ~ RTT/2 ----
        if (l > 0 && w == 7) {
            const unsigned lim = (unsigned)l;
            unsigned fa, fb; int guard = 0;
            asm volatile("global_load_dword %0, %1, off sc0 sc1" : "=v"(fa) : "v"(pollflag) : "memory");
            __builtin_amdgcn_s_sleep(8);   // ~0.2us: spread the two streams
            for (;;) {
                asm volatile("global_load_dword %0, %1, off sc0 sc1" : "=v"(fb) : "v"(pollflag) : "memory");
                asm volatile("s_waitcnt vmcnt(1)" ::: "memory");
                __builtin_amdgcn_sched_barrier(0);   // rule #18: pin check after wait
                if (!__any(fa < lim) || ++guard >= (1 << 18)) break;
                asm volatile("global_load_dword %0, %1, off sc0 sc1" : "=v"(fa) : "v"(pollflag) : "memory");
                asm volatile("s_waitcnt vmcnt(1)" ::: "memory");
                __builtin_amdgcn_sched_barrier(0);
                if (!__any(fb < lim) || ++guard >= (1 << 18)) break;
            }
            asm volatile("s_waitcnt vmcnt(0)" ::: "memory");   // drain the leftover load
        }
        __syncthreads();   // B1

        // ---- UC h read + recurrent GEMM ----
        short8 af[8];
        const unsigned short* hp = hr + (size_t)(b0 + d) * HH + ksl * 256 + rg * 8;
        #pragma unroll
        for (int kf = 0; kf < 8; ++kf) af[kf] = uc_load128(hp + kf * 32);
        asm volatile("s_waitcnt vmcnt(0)" ::: "memory");
        __builtin_amdgcn_sched_barrier(0);

        #pragma unroll
        for (int kf = 0; kf < 8; ++kf)
            #pragma unroll
            for (int t = 0; t < 4; ++t)
                acc[t] = __builtin_amdgcn_mfma_f32_16x16x32_bf16(af[kf], breg[t][kf], acc[t], 0, 0, 0);

        if (ksl != 0) {
            float* sp = &red[(size_t)((nq * 3 + (ksl - 1)) * 64 + lane) * 17];
            #pragma unroll
            for (int t = 0; t < 4; ++t)
                #pragma unroll
                for (int r = 0; r < 4; ++r) sp[t * 4 + r] = acc[t][r];
        }
        __syncthreads();   // B2: partials ready

        // ---- gate waves: absorb, gate math, hbuf write; NO global stores here ----
        float h1v[4];
        if (ksl == 0) {
            #pragma unroll
            for (int s = 0; s < 3; ++s) {
                const float* sp = &red[(size_t)((nq * 3 + s) * 64 + lane) * 17];
                #pragma unroll
                for (int t = 0; t < 4; ++t)
                    #pragma unroll
                    for (int r = 0; r < 4; ++r) acc[t][r] += sp[t * 4 + r];
            }
            #pragma unroll
            for (int r = 0; r < 4; ++r) {
                float gi = acc[0][r] + base_r[0 + r];
                float gf = acc[1][r] + base_r[4 + r];
                float gg = acc[2][r] + base_r[8 + r];
                float go = acc[3][r] + base_r[12 + r];
                float ig = fast_sigmoid(gi);
                float fg = fast_sigmoid(gf);
                float og = fast_sigmoid(go);
                float gt = fast_tanh(gg);
                float c1 = fg * c_r[r] + ig * gt;
                float h1 = og * fast_tanh(c1);
                c_r[r] = c1;
                h1v[r] = h1;
                hbuf[(rg * 4 + r) * 32 + nq * 16 + d] = f2b(h1);
            }
        }
        __syncthreads();   // sync2: hbuf ready (empty vmcnt drain — no stores pending)

        // wave 2 (idle otherwise): line-dense h store (16 rows x 64 B) + flag
        if (w == 2 && l < LL - 1) {
            int row = lane >> 2, ch = lane & 3;
            uint32x4 hv = *(const uint32x4*)&hbuf[row * 32 + ch * 8];
            uc_store128(&hw[(size_t)(b0 + row) * HH + j0 + ch * 8], hv);
            asm volatile("s_waitcnt vmcnt(0)" ::: "memory");   // ONLY the h store in flight
            if (lane == 0) uc_flag_store(ourflag, (unsigned)(l + 1));
        }

        // ---- deferred out[] stores: drain later, under next step's poll wait ----
        if (ksl == 0) {
            #pragma unroll
            for (int r = 0; r < 4; ++r)
                out[((size_t)l * BB + (b0 + rg * 4 + r)) * HH + j0 + nq * 16 + d] = h1v[r];
            if (l == LL - 1) {
                #pragma unroll
                for (int r = 0; r < 4; ++r) {
                    out[(size_t)LL * BB * HH + (b0 + rg * 4 + r) * HH + j0 + nq * 16 + d] = h1v[r];
                    out[(size_t)LL * BB * HH + BB * HH + (b0 + rg * 4 + r) * HH + j0 + nq * 16 + d] = c_r[r];
                }
            }
        }
    }
}

extern "C" void kernel_launch(void* const* d_in, const int* in_sizes, int n_in,
                              void* d_out, int out_size, void* d_ws, size_t ws_size,
                              hipStream_t stream) {
    const float* act = (const float*)d_in[0];
    const float* inF = (const float*)d_in[1];
    const float* h0  = (const float*)d_in[2];
    const float* c0  = (const float*)d_in[3];
    const float* Wih = (const float*)d_in[4];
    const float* Whh = (const float*)d_in[5];
    const float* bih = (const float*)d_in[6];
    const float* bhh = (const float*)d_in[7];
    float* out = (float*)d_out;

    char* p = (char*)d_ws;
    unsigned short* xa    = (unsigned short*)p; p += (size_t)LL * BB * AA * 2;   // 16.8 MB
    unsigned short* wihb  = (unsigned short*)p; p += (size_t)4 * HH * KK * 2;    //  8.4 MB
    unsigned short* whhb  = (unsigned short*)p; p += (size_t)4 * HH * HH * 2;    //  8.4 MB
    unsigned short* hb    = (unsigned short*)p; p += (size_t)2 * BB * HH * 2;    //  0.5 MB
    unsigned int*   flags = (unsigned int*)p;   p += NTEAM * NDG * sizeof(unsigned int);

    hipMemsetAsync(flags, 0, NTEAM * NDG * sizeof(unsigned int), stream);
    cast_kernel<<<dim3(2048), dim3(256), 0, stream>>>(act, xa, LL * BB * AA);
    cast_kernel<<<dim3(1024), dim3(256), 0, stream>>>(Wih, wihb, 4 * HH * KK);
    cast_kernel<<<dim3(1024), dim3(256), 0, stream>>>(Whh, whhb, 4 * HH * HH);
    cast_kernel<<<dim3(64), dim3(256), 0, stream>>>(h0, hb, BB * HH);

    void* args[] = { (void*)&xa, (void*)&inF, (void*)&wihb, (void*)&whhb, (void*)&bih,
                     (void*)&bhh, (void*)&c0, (void*)&hb, (void*)&flags, (void*)&out };
    hipLaunchCooperativeKernel((const void*)lstm_kernel, dim3(NBLK), dim3(512), args, 0, stream);
}